// Round 1
// baseline (193.997 us; speedup 1.0000x reference)
//
#include <hip/hip_runtime.h>

#define KNB 31
#define CH 64
#define TEMP_INV 10.0f   // 1 / temperature(0.1)

// ---------------------------------------------------------------------------
// ws layout (doubles): ws[0] = sum(loss * point_mask), ws[1] = sum(point_mask)
// ---------------------------------------------------------------------------

__global__ void ch_init_ws(double* __restrict__ ws) {
    ws[0] = 0.0;
    ws[1] = 0.0;
}

__global__ __launch_bounds__(256) void ch_main(
    const float* __restrict__ feat,     // (N, 64) f32
    const int*   __restrict__ labels,   // (N,)    i32
    const int*   __restrict__ nidx,     // (N, 31) i32
    double*      __restrict__ ws,
    int n)
{
    const int i = blockIdx.x * blockDim.x + threadIdx.x;

    float loss_w = 0.0f;   // loss * point_mask
    float pm_f   = 0.0f;   // point_mask

    if (i < n) {
        // own feature row -> 16 x float4 registers (reused for all 31 neighbors)
        const float4* fp = reinterpret_cast<const float4*>(feat + (size_t)i * CH);
        float4 f[CH / 4];
        #pragma unroll
        for (int q = 0; q < CH / 4; ++q) f[q] = fp[q];

        const int lab = labels[i];

        // online softmax state (logit l = -dist; scaled by 1/T at exp time)
        float m  = -1e30f;  // running max logit
        float se = 0.0f;    // sum exp
        float sp = 0.0f;    // sum exp * posmask
        int   cnt = 0;

        #pragma unroll 2
        for (int j = 0; j < KNB; ++j) {
            const int nj = nidx[(size_t)i * KNB + j];
            const float4* gp = reinterpret_cast<const float4*>(feat + (size_t)nj * CH);

            float s = 0.0f;
            #pragma unroll
            for (int q = 0; q < CH / 4; ++q) {
                const float4 v = gp[q];
                const float dx = f[q].x - v.x;
                const float dy = f[q].y - v.y;
                const float dz = f[q].z - v.z;
                const float dw = f[q].w - v.w;
                s += dx * dx + dy * dy + dz * dz + dw * dw;
            }
            const float dist = sqrtf(s) + 1e-8f;
            const float l = -dist;

            const bool pm = (labels[nj] == lab);
            cnt += pm ? 1 : 0;

            // online softmax update (matches max-subtract-then-exp exactly)
            if (l > m) {
                const float r = __expf((m - l) * TEMP_INV);
                se *= r;
                sp *= r;
                m = l;
            }
            const float e = __expf((l - m) * TEMP_INV);
            se += e;
            if (pm) sp += e;
        }

        if (cnt > 0 && cnt < KNB) {
            loss_w = -logf(sp / se + 1e-8f);
            pm_f   = 1.0f;
        }
    }

    // block reduction (LDS), then one double atomic per block
    __shared__ float s_l[256];
    __shared__ float s_c[256];
    const int t = threadIdx.x;
    s_l[t] = loss_w;
    s_c[t] = pm_f;
    __syncthreads();
    #pragma unroll
    for (int off = 128; off > 0; off >>= 1) {
        if (t < off) {
            s_l[t] += s_l[t + off];
            s_c[t] += s_c[t + off];
        }
        __syncthreads();
    }
    if (t == 0) {
        atomicAdd(ws,     (double)s_l[0]);
        atomicAdd(ws + 1, (double)s_c[0]);
    }
}

__global__ void ch_finalize(const double* __restrict__ ws, float* __restrict__ out) {
    double c = ws[1];
    if (c < 1.0) c = 1.0;
    out[0] = (float)(ws[0] / c);   // WEIGHT = 1.0
}

extern "C" void kernel_launch(void* const* d_in, const int* in_sizes, int n_in,
                              void* d_out, int out_size, void* d_ws, size_t ws_size,
                              hipStream_t stream) {
    const float* feat   = (const float*)d_in[0];
    const int*   labels = (const int*)d_in[1];
    const int*   nidx   = (const int*)d_in[2];
    float*       out    = (float*)d_out;
    double*      ws     = (double*)d_ws;

    const int n = in_sizes[1];           // N = 100000 (labels count)

    ch_init_ws<<<1, 1, 0, stream>>>(ws);
    const int blocks = (n + 255) / 256;
    ch_main<<<blocks, 256, 0, stream>>>(feat, labels, nidx, ws, n);
    ch_finalize<<<1, 1, 0, stream>>>(ws, out);
}

// Round 2
// 93.510 us; speedup vs baseline: 2.0746x; 2.0746x over previous
//
#include <hip/hip_runtime.h>
#include <hip/hip_fp16.h>

#define KNB 31
#define CH 64
#define TEMP_INV 10.0f   // 1 / temperature(0.1)

// ---------------------------------------------------------------------------
// ws layout:
//   bytes [0, 16)        : double ws[2]  (sum(loss*mask), sum(mask))
//   bytes [256, 256+2NC) : __half feature table (fp16 path only)
// ---------------------------------------------------------------------------

__global__ void ch_init_ws(double* __restrict__ ws) {
    ws[0] = 0.0;
    ws[1] = 0.0;
}

// features f32 -> fp16 table, 8 floats per thread
__global__ __launch_bounds__(256) void ch_cvt(
    const float* __restrict__ in, __half* __restrict__ out, int total8)
{
    const int idx = blockIdx.x * blockDim.x + threadIdx.x;
    if (idx >= total8) return;
    const float4* ip = reinterpret_cast<const float4*>(in) + (size_t)idx * 2;
    const float4 a = ip[0];
    const float4 b = ip[1];
    union { uint4 u; __half2 h[4]; } o;
    o.h[0] = __floats2half2_rn(a.x, a.y);
    o.h[1] = __floats2half2_rn(a.z, a.w);
    o.h[2] = __floats2half2_rn(b.x, b.y);
    o.h[3] = __floats2half2_rn(b.z, b.w);
    reinterpret_cast<uint4*>(out)[idx] = o.u;
}

// 4 lanes per point: lane sub in [0,4) owns 16 channels.
template <bool FP16>
__global__ __launch_bounds__(256) void ch_main4(
    const float*  __restrict__ feat,    // (N, 64) f32
    const __half* __restrict__ tab,     // (N, 64) fp16 (valid iff FP16)
    const int*    __restrict__ labels,  // (N,)
    const int*    __restrict__ nidx,    // (N, 31)
    double*       __restrict__ ws,
    int n)
{
    const int t   = threadIdx.x;
    const int i   = blockIdx.x * (256 / 4) + (t >> 2);
    const int sub = t & 3;

    float loss_w = 0.0f;
    float pm_f   = 0.0f;

    if (i < n) {
        // own 16 channels -> registers (reused across all 31 neighbors)
        float f[16];
        if constexpr (FP16) {
            union { uint4 u[2]; __half2 h[8]; } a;
            const uint4* ap = reinterpret_cast<const uint4*>(tab + (size_t)i * CH + sub * 16);
            a.u[0] = ap[0];
            a.u[1] = ap[1];
            #pragma unroll
            for (int q = 0; q < 8; ++q) {
                const float2 v = __half22float2(a.h[q]);
                f[2 * q]     = v.x;
                f[2 * q + 1] = v.y;
            }
        } else {
            const float4* ap = reinterpret_cast<const float4*>(feat + (size_t)i * CH + sub * 16);
            #pragma unroll
            for (int q = 0; q < 4; ++q) {
                const float4 v = ap[q];
                f[4 * q]     = v.x;
                f[4 * q + 1] = v.y;
                f[4 * q + 2] = v.z;
                f[4 * q + 3] = v.w;
            }
        }

        const int lab = labels[i];

        float m  = -1e30f;  // running max logit
        float se = 0.0f;
        float sp = 0.0f;
        int   cnt = 0;

        #pragma unroll 2
        for (int j = 0; j < KNB; ++j) {
            const int nj = nidx[(size_t)i * KNB + j];  // same addr across quad -> broadcast

            float s = 0.0f;
            if constexpr (FP16) {
                union { uint4 u[2]; __half2 h[8]; } b;
                const uint4* bp = reinterpret_cast<const uint4*>(tab + (size_t)nj * CH + sub * 16);
                b.u[0] = bp[0];
                b.u[1] = bp[1];
                #pragma unroll
                for (int q = 0; q < 8; ++q) {
                    const float2 v = __half22float2(b.h[q]);
                    const float dx = f[2 * q]     - v.x;
                    const float dy = f[2 * q + 1] - v.y;
                    s += dx * dx + dy * dy;
                }
            } else {
                const float4* bp = reinterpret_cast<const float4*>(feat + (size_t)nj * CH + sub * 16);
                #pragma unroll
                for (int q = 0; q < 4; ++q) {
                    const float4 v = bp[q];
                    const float dx = f[4 * q]     - v.x;
                    const float dy = f[4 * q + 1] - v.y;
                    const float dz = f[4 * q + 2] - v.z;
                    const float dw = f[4 * q + 3] - v.w;
                    s += dx * dx + dy * dy + dz * dz + dw * dw;
                }
            }
            // close dist^2 across the quad
            s += __shfl_xor(s, 1);
            s += __shfl_xor(s, 2);

            const float dist = sqrtf(s) + 1e-8f;
            const float l = -dist;

            const bool pm = (labels[nj] == lab);  // broadcast within quad
            cnt += pm ? 1 : 0;

            if (l > m) {
                const float r = __expf((m - l) * TEMP_INV);
                se *= r;
                sp *= r;
                m = l;
            }
            const float e = __expf((l - m) * TEMP_INV);
            se += e;
            if (pm) sp += e;
        }

        if (sub == 0 && cnt > 0 && cnt < KNB) {
            loss_w = -logf(sp / se + 1e-8f);
            pm_f   = 1.0f;
        }
    }

    __shared__ float s_l[256];
    __shared__ float s_c[256];
    s_l[t] = loss_w;
    s_c[t] = pm_f;
    __syncthreads();
    #pragma unroll
    for (int off = 128; off > 0; off >>= 1) {
        if (t < off) {
            s_l[t] += s_l[t + off];
            s_c[t] += s_c[t + off];
        }
        __syncthreads();
    }
    if (t == 0) {
        atomicAdd(ws,     (double)s_l[0]);
        atomicAdd(ws + 1, (double)s_c[0]);
    }
}

__global__ void ch_finalize(const double* __restrict__ ws, float* __restrict__ out) {
    double c = ws[1];
    if (c < 1.0) c = 1.0;
    out[0] = (float)(ws[0] / c);   // WEIGHT = 1.0
}

extern "C" void kernel_launch(void* const* d_in, const int* in_sizes, int n_in,
                              void* d_out, int out_size, void* d_ws, size_t ws_size,
                              hipStream_t stream) {
    const float* feat   = (const float*)d_in[0];
    const int*   labels = (const int*)d_in[1];
    const int*   nidx   = (const int*)d_in[2];
    float*       out    = (float*)d_out;
    double*      ws     = (double*)d_ws;

    const int n = in_sizes[1];                 // N = 100000
    const size_t tab_bytes = (size_t)n * CH * sizeof(__half);
    const bool fp16_ok = ws_size >= 256 + tab_bytes;

    ch_init_ws<<<1, 1, 0, stream>>>(ws);

    const int blocks = (n + 63) / 64;          // 64 points per 256-thread block
    if (fp16_ok) {
        __half* tab = reinterpret_cast<__half*>((char*)d_ws + 256);
        const int total8 = n * CH / 8;
        ch_cvt<<<(total8 + 255) / 256, 256, 0, stream>>>(feat, tab, total8);
        ch_main4<true><<<blocks, 256, 0, stream>>>(feat, tab, labels, nidx, ws, n);
    } else {
        ch_main4<false><<<blocks, 256, 0, stream>>>(feat, nullptr, labels, nidx, ws, n);
    }

    ch_finalize<<<1, 1, 0, stream>>>(ws, out);
}